// Round 1
// baseline (8138.592 us; speedup 1.0000x reference)
//
#include <hip/hip_runtime.h>
#include <math.h>

#define IDIM 32
#define HDIM 64
#define KNN 16
#define NPTS 8192
#define NBATCH 16
#define CLAMPV 1.9f
#define TWO_OVER_PI 0.63661977236758134f

// ---------------------------------------------------------------------------
// ws layout (floats): WA[4][16][64] at 0, WB[4][16][64] at 4096
//   WA = W1[:, 0:16, :]  - W1[:, 32:48, :]   (ctr coefficient, folded)
//   WB = W1[:, 16:32, :] + W1[:, 32:48, :]   (nb  coefficient, folded)
// ---------------------------------------------------------------------------
__global__ void prep_weights(const float* __restrict__ W1, float* __restrict__ ws) {
    int e = blockIdx.x * 256 + threadIdx.x;   // 0 .. 4095
    if (e >= 4 * 16 * 64) return;
    int u = e >> 10;
    int r = e & 1023;
    const float* base = W1 + u * 3072;        // (48,64) row-major
    float a = base[r];                        // rows 0..15  (ctr)
    float b = base[1024 + r];                 // rows 16..31 (nb)
    float c = base[2048 + r];                 // rows 32..47 (nb-ctr)
    ws[e]        = a - c;                     // WA
    ws[4096 + e] = b + c;                     // WB
}

// ---------------------------------------------------------------------------
// z[b,n,d] = x[b,n,31-d] * exp(an_logs[d]) + an_bias[d]   (one thread per row)
// Also initializes log_det[b] = sum(an_logs) * N.
// ---------------------------------------------------------------------------
__global__ void affine_rev(const float* __restrict__ x, const float* __restrict__ logs,
                           const float* __restrict__ bias, float* __restrict__ out) {
    __shared__ float ssc[IDIM], sbi[IDIM];
    int tid = threadIdx.x;
    if (tid < IDIM) { ssc[tid] = expf(logs[tid]); sbi[tid] = bias[tid]; }
    __syncthreads();

    size_t p = (size_t)blockIdx.x * blockDim.x + tid;  // point row index
    if (p < (size_t)NBATCH * NPTS) {
        const float4* xr = (const float4*)(x + p * IDIM);
        float xv[IDIM];
#pragma unroll
        for (int q = 0; q < 8; ++q) {
            float4 v = xr[q];
            xv[q * 4 + 0] = v.x; xv[q * 4 + 1] = v.y;
            xv[q * 4 + 2] = v.z; xv[q * 4 + 3] = v.w;
        }
        float zv[IDIM];
#pragma unroll
        for (int d = 0; d < IDIM; ++d) zv[d] = xv[IDIM - 1 - d] * ssc[d] + sbi[d];
        float4* zr = (float4*)(out + p * IDIM);
#pragma unroll
        for (int q = 0; q < 8; ++q) {
            float4 v;
            v.x = zv[q * 4 + 0]; v.y = zv[q * 4 + 1];
            v.z = zv[q * 4 + 2]; v.w = zv[q * 4 + 3];
            zr[q] = v;
        }
    }
    if (blockIdx.x == 0 && tid < NBATCH) {
        float sl = 0.f;
#pragma unroll
        for (int d = 0; d < IDIM; ++d) sl += logs[d];
        out[(size_t)NBATCH * NPTS * IDIM + tid] = sl * (float)NPTS;
    }
}

// ---------------------------------------------------------------------------
// Heavy kernel: one thread per (point, k). 16-lane groups reduce over K.
// Four MLPs share the gathered features. z2 is updated twice (u=0/1, u=2/3).
// ---------------------------------------------------------------------------
__global__ void knn_flow(const int* __restrict__ knn,
                         const float* __restrict__ WAB,   // ws: WA | WB
                         const float* __restrict__ B1, const float* __restrict__ W2,
                         const float* __restrict__ B2, const float* __restrict__ W3,
                         const float* __restrict__ B3,
                         float* __restrict__ out) {
    int gid = blockIdx.x * 256 + threadIdx.x;
    int p = gid >> 4;            // point index (b*N + n)
    int k = gid & 15;            // neighbor slot
    int b = p >> 13;             // N = 8192

    float* zrow = out + (size_t)p * IDIM;
    int idx = knn[(size_t)p * KNN + k];
    const float* nrow = out + ((size_t)(b * NPTS) + (size_t)idx) * IDIM;

    // center (z1) and neighbor (z1) features, 16 floats each
    float cc[16], nb[16];
    {
        const float4* cr = (const float4*)zrow;
        const float4* nr = (const float4*)nrow;
#pragma unroll
        for (int q = 0; q < 4; ++q) {
            float4 v = cr[q];
            cc[q * 4 + 0] = v.x; cc[q * 4 + 1] = v.y; cc[q * 4 + 2] = v.z; cc[q * 4 + 3] = v.w;
        }
#pragma unroll
        for (int q = 0; q < 4; ++q) {
            float4 v = nr[q];
            nb[q * 4 + 0] = v.x; nb[q * 4 + 1] = v.y; nb[q * 4 + 2] = v.z; nb[q * 4 + 3] = v.w;
        }
    }

    float z2[16];
    float sum_s = 0.f;

#pragma unroll 1
    for (int pair = 0; pair < 2; ++pair) {
        float sraw[16], traw[16];
#pragma unroll 1
        for (int half = 0; half < 2; ++half) {
            int u = pair * 2 + half;
            const float* wa  = WAB + u * 1024;
            const float* wb  = WAB + 4096 + u * 1024;
            const float* w2  = W2 + u * 4096;
            const float* w3  = W3 + u * 1024;
            const float* bb1 = B1 + u * 64;
            const float* bb2 = B2 + u * 64;
            const float* bb3 = B3 + u * 16;

            float h1[64];
#pragma unroll
            for (int j = 0; j < 64; ++j) h1[j] = bb1[j];
#pragma unroll
            for (int i = 0; i < 16; ++i) {
                float a = cc[i];
#pragma unroll
                for (int j = 0; j < 64; ++j) h1[j] += a * wa[i * 64 + j];
            }
#pragma unroll
            for (int i = 0; i < 16; ++i) {
                float a = nb[i];
#pragma unroll
                for (int j = 0; j < 64; ++j) h1[j] += a * wb[i * 64 + j];
            }
#pragma unroll
            for (int j = 0; j < 64; ++j) h1[j] = fmaxf(h1[j], 0.f);

            float h2[64];
#pragma unroll
            for (int j = 0; j < 64; ++j) h2[j] = bb2[j];
#pragma unroll
            for (int i = 0; i < 64; ++i) {
                float a = h1[i];
#pragma unroll
                for (int j = 0; j < 64; ++j) h2[j] += a * w2[i * 64 + j];
            }
#pragma unroll
            for (int j = 0; j < 64; ++j) h2[j] = fmaxf(h2[j], 0.f);

            float o[16];
#pragma unroll
            for (int j = 0; j < 16; ++j) o[j] = bb3[j];
#pragma unroll
            for (int i = 0; i < 64; ++i) {
                float a = h2[i];
#pragma unroll
                for (int j = 0; j < 16; ++j) o[j] += a * w3[i * 16 + j];
            }

            // max over the 16-lane K group (butterfly; all lanes end with max)
#pragma unroll
            for (int j = 0; j < 16; ++j) {
                float v = o[j];
                v = fmaxf(v, __shfl_xor(v, 1, 16));
                v = fmaxf(v, __shfl_xor(v, 2, 16));
                v = fmaxf(v, __shfl_xor(v, 4, 16));
                v = fmaxf(v, __shfl_xor(v, 8, 16));
                o[j] = v;
            }

            if (half == 0) {
#pragma unroll
                for (int j = 0; j < 16; ++j) sraw[j] = o[j];
            } else {
#pragma unroll
                for (int j = 0; j < 16; ++j) traw[j] = o[j];
            }
        }

        if (pair == 0) {
            const float4* z2r = (const float4*)(zrow + 16);
#pragma unroll
            for (int q = 0; q < 4; ++q) {
                float4 v = z2r[q];
                z2[q * 4 + 0] = v.x; z2[q * 4 + 1] = v.y;
                z2[q * 4 + 2] = v.z; z2[q * 4 + 3] = v.w;
            }
        }

#pragma unroll
        for (int j = 0; j < 16; ++j) {
            float s = CLAMPV * TWO_OVER_PI * atanf(sraw[j] * (1.0f / CLAMPV));
            sum_s += s;
            z2[j] = z2[j] * expf(s) + traw[j];
        }
    }

    if (k == 0) {
        float4* z2w = (float4*)(zrow + 16);
#pragma unroll
        for (int q = 0; q < 4; ++q) {
            float4 v;
            v.x = z2[q * 4 + 0]; v.y = z2[q * 4 + 1];
            v.z = z2[q * 4 + 2]; v.w = z2[q * 4 + 3];
            z2w[q] = v;
        }
        atomicAdd(out + (size_t)NBATCH * NPTS * IDIM + b, sum_s);
    }
}

extern "C" void kernel_launch(void* const* d_in, const int* in_sizes, int n_in,
                              void* d_out, int out_size, void* d_ws, size_t ws_size,
                              hipStream_t stream) {
    const float* x    = (const float*)d_in[0];
    const int*   knn  = (const int*)d_in[1];
    const float* logs = (const float*)d_in[2];
    const float* bias = (const float*)d_in[3];
    const float* W1   = (const float*)d_in[4];
    const float* b1   = (const float*)d_in[5];
    const float* W2   = (const float*)d_in[6];
    const float* b2   = (const float*)d_in[7];
    const float* W3   = (const float*)d_in[8];
    const float* b3   = (const float*)d_in[9];
    float* out = (float*)d_out;
    float* ws  = (float*)d_ws;

    hipLaunchKernelGGL(prep_weights, dim3(16), dim3(256), 0, stream, W1, ws);
    hipLaunchKernelGGL(affine_rev, dim3(512), dim3(256), 0, stream, x, logs, bias, out);
    hipLaunchKernelGGL(knn_flow, dim3(8192), dim3(256), 0, stream,
                       knn, ws, b1, W2, b2, W3, b3, out);
}

// Round 2
// 2515.119 us; speedup vs baseline: 3.2359x; 3.2359x over previous
//
#include <hip/hip_runtime.h>
#include <math.h>

#define IDIM 32
#define HDIM 64
#define KNN 16
#define NPTS 8192
#define NBATCH 16
#define CLAMPV 1.9f
#define TWO_OVER_PI 0.63661977236758134f

// ---------------------------------------------------------------------------
// ws layout (floats): WA[4][16][64] at 0, WB[4][16][64] at 4096
//   WA = W1[:, 0:16, :]  - W1[:, 32:48, :]   (ctr coefficient, folded)
//   WB = W1[:, 16:32, :] + W1[:, 32:48, :]   (nb  coefficient, folded)
// ---------------------------------------------------------------------------
__global__ void prep_weights(const float* __restrict__ W1, float* __restrict__ ws) {
    int e = blockIdx.x * 256 + threadIdx.x;   // 0 .. 4095
    if (e >= 4 * 16 * 64) return;
    int u = e >> 10;
    int r = e & 1023;
    const float* base = W1 + u * 3072;        // (48,64) row-major
    float a = base[r];                        // rows 0..15  (ctr)
    float b = base[1024 + r];                 // rows 16..31 (nb)
    float c = base[2048 + r];                 // rows 32..47 (nb-ctr)
    ws[e]        = a - c;                     // WA
    ws[4096 + e] = b + c;                     // WB
}

// ---------------------------------------------------------------------------
// z[b,n,d] = x[b,n,31-d] * exp(an_logs[d]) + an_bias[d]   (one thread per row)
// Also initializes log_det[b] = sum(an_logs) * N.
// ---------------------------------------------------------------------------
__global__ void affine_rev(const float* __restrict__ x, const float* __restrict__ logs,
                           const float* __restrict__ bias, float* __restrict__ out) {
    __shared__ float ssc[IDIM], sbi[IDIM];
    int tid = threadIdx.x;
    if (tid < IDIM) { ssc[tid] = expf(logs[tid]); sbi[tid] = bias[tid]; }
    __syncthreads();

    size_t p = (size_t)blockIdx.x * blockDim.x + tid;  // point row index
    if (p < (size_t)NBATCH * NPTS) {
        const float4* xr = (const float4*)(x + p * IDIM);
        float xv[IDIM];
#pragma unroll
        for (int q = 0; q < 8; ++q) {
            float4 v = xr[q];
            xv[q * 4 + 0] = v.x; xv[q * 4 + 1] = v.y;
            xv[q * 4 + 2] = v.z; xv[q * 4 + 3] = v.w;
        }
        float zv[IDIM];
#pragma unroll
        for (int d = 0; d < IDIM; ++d) zv[d] = xv[IDIM - 1 - d] * ssc[d] + sbi[d];
        float4* zr = (float4*)(out + p * IDIM);
#pragma unroll
        for (int q = 0; q < 8; ++q) {
            float4 v;
            v.x = zv[q * 4 + 0]; v.y = zv[q * 4 + 1];
            v.z = zv[q * 4 + 2]; v.w = zv[q * 4 + 3];
            zr[q] = v;
        }
    }
    if (blockIdx.x == 0 && tid < NBATCH) {
        float sl = 0.f;
#pragma unroll
        for (int d = 0; d < IDIM; ++d) sl += logs[d];
        out[(size_t)NBATCH * NPTS * IDIM + tid] = sl * (float)NPTS;
    }
}

// ---------------------------------------------------------------------------
// Heavy kernel: one thread per (point, k). 16-lane groups reduce over K.
// __launch_bounds__(256, 1): min 1 wave/EU -> ~512 VGPR budget so h1[64]/h2[64]
// live fully in registers (round-1 version was capped at 64 VGPR and spilled
// ~3 GB of scratch traffic to HBM).
// ---------------------------------------------------------------------------
__global__ __launch_bounds__(256, 1)
void knn_flow(const int* __restrict__ knn,
              const float* __restrict__ WAB,   // ws: WA | WB
              const float* __restrict__ B1, const float* __restrict__ W2,
              const float* __restrict__ B2, const float* __restrict__ W3,
              const float* __restrict__ B3,
              float* __restrict__ out) {
    int gid = blockIdx.x * 256 + threadIdx.x;
    int p = gid >> 4;            // point index (b*N + n)
    int k = gid & 15;            // neighbor slot
    int b = p >> 13;             // N = 8192

    float* zrow = out + (size_t)p * IDIM;
    int idx = knn[(size_t)p * KNN + k];
    const float* nrow = out + ((size_t)(b * NPTS) + (size_t)idx) * IDIM;

    // center (z1) and neighbor (z1) features, 16 floats each
    float cc[16], nb[16];
    {
        const float4* cr = (const float4*)zrow;
        const float4* nr = (const float4*)nrow;
#pragma unroll
        for (int q = 0; q < 4; ++q) {
            float4 v = cr[q];
            cc[q * 4 + 0] = v.x; cc[q * 4 + 1] = v.y; cc[q * 4 + 2] = v.z; cc[q * 4 + 3] = v.w;
        }
#pragma unroll
        for (int q = 0; q < 4; ++q) {
            float4 v = nr[q];
            nb[q * 4 + 0] = v.x; nb[q * 4 + 1] = v.y; nb[q * 4 + 2] = v.z; nb[q * 4 + 3] = v.w;
        }
    }

    float z2[16];
    float sum_s = 0.f;

#pragma unroll 1
    for (int pair = 0; pair < 2; ++pair) {
        float sraw[16], traw[16];
#pragma unroll 1
        for (int half = 0; half < 2; ++half) {
            int u = pair * 2 + half;
            const float* wa  = WAB + u * 1024;
            const float* wb  = WAB + 4096 + u * 1024;
            const float* w2  = W2 + u * 4096;
            const float* w3  = W3 + u * 1024;
            const float* bb1 = B1 + u * 64;
            const float* bb2 = B2 + u * 64;
            const float* bb3 = B3 + u * 16;

            float h1[64];
#pragma unroll
            for (int j = 0; j < 64; ++j) h1[j] = bb1[j];
#pragma unroll
            for (int i = 0; i < 16; ++i) {
                float a = cc[i];
#pragma unroll
                for (int j = 0; j < 64; ++j) h1[j] += a * wa[i * 64 + j];
            }
#pragma unroll
            for (int i = 0; i < 16; ++i) {
                float a = nb[i];
#pragma unroll
                for (int j = 0; j < 64; ++j) h1[j] += a * wb[i * 64 + j];
            }
#pragma unroll
            for (int j = 0; j < 64; ++j) h1[j] = fmaxf(h1[j], 0.f);

            float h2[64];
#pragma unroll
            for (int j = 0; j < 64; ++j) h2[j] = bb2[j];
#pragma unroll
            for (int i = 0; i < 64; ++i) {
                float a = h1[i];
#pragma unroll
                for (int j = 0; j < 64; ++j) h2[j] += a * w2[i * 64 + j];
            }
#pragma unroll
            for (int j = 0; j < 64; ++j) h2[j] = fmaxf(h2[j], 0.f);

            float o[16];
#pragma unroll
            for (int j = 0; j < 16; ++j) o[j] = bb3[j];
#pragma unroll
            for (int i = 0; i < 64; ++i) {
                float a = h2[i];
#pragma unroll
                for (int j = 0; j < 16; ++j) o[j] += a * w3[i * 16 + j];
            }

            // max over the 16-lane K group (butterfly; all lanes end with max)
#pragma unroll
            for (int j = 0; j < 16; ++j) {
                float v = o[j];
                v = fmaxf(v, __shfl_xor(v, 1, 16));
                v = fmaxf(v, __shfl_xor(v, 2, 16));
                v = fmaxf(v, __shfl_xor(v, 4, 16));
                v = fmaxf(v, __shfl_xor(v, 8, 16));
                o[j] = v;
            }

            if (half == 0) {
#pragma unroll
                for (int j = 0; j < 16; ++j) sraw[j] = o[j];
            } else {
#pragma unroll
                for (int j = 0; j < 16; ++j) traw[j] = o[j];
            }
        }

        if (pair == 0) {
            const float4* z2r = (const float4*)(zrow + 16);
#pragma unroll
            for (int q = 0; q < 4; ++q) {
                float4 v = z2r[q];
                z2[q * 4 + 0] = v.x; z2[q * 4 + 1] = v.y;
                z2[q * 4 + 2] = v.z; z2[q * 4 + 3] = v.w;
            }
        }

#pragma unroll
        for (int j = 0; j < 16; ++j) {
            float s = CLAMPV * TWO_OVER_PI * atanf(sraw[j] * (1.0f / CLAMPV));
            sum_s += s;
            z2[j] = z2[j] * expf(s) + traw[j];
        }
    }

    if (k == 0) {
        float4* z2w = (float4*)(zrow + 16);
#pragma unroll
        for (int q = 0; q < 4; ++q) {
            float4 v;
            v.x = z2[q * 4 + 0]; v.y = z2[q * 4 + 1];
            v.z = z2[q * 4 + 2]; v.w = z2[q * 4 + 3];
            z2w[q] = v;
        }
        atomicAdd(out + (size_t)NBATCH * NPTS * IDIM + b, sum_s);
    }
}

extern "C" void kernel_launch(void* const* d_in, const int* in_sizes, int n_in,
                              void* d_out, int out_size, void* d_ws, size_t ws_size,
                              hipStream_t stream) {
    const float* x    = (const float*)d_in[0];
    const int*   knn  = (const int*)d_in[1];
    const float* logs = (const float*)d_in[2];
    const float* bias = (const float*)d_in[3];
    const float* W1   = (const float*)d_in[4];
    const float* b1   = (const float*)d_in[5];
    const float* W2   = (const float*)d_in[6];
    const float* b2   = (const float*)d_in[7];
    const float* W3   = (const float*)d_in[8];
    const float* b3   = (const float*)d_in[9];
    float* out = (float*)d_out;
    float* ws  = (float*)d_ws;

    hipLaunchKernelGGL(prep_weights, dim3(16), dim3(256), 0, stream, W1, ws);
    hipLaunchKernelGGL(affine_rev, dim3(512), dim3(256), 0, stream, x, logs, bias, out);
    hipLaunchKernelGGL(knn_flow, dim3(8192), dim3(256), 0, stream,
                       knn, ws, b1, W2, b2, W3, b3, out);
}

// Round 3
// 491.984 us; speedup vs baseline: 16.5424x; 5.1122x over previous
//
#include <hip/hip_runtime.h>
#include <math.h>

#define IDIM 32
#define KNN 16
#define NPTS 8192
#define NBATCH 16
#define PPB 16                      // points per block (4 waves x 4 groups epilogue)
#define CLAMPV 1.9f
#define TWO_OVER_PI 0.63661977236758134f

typedef __attribute__((ext_vector_type(8))) short bf16x8;   // 8 bf16 = 4 VGPR (MFMA A/B)
typedef __attribute__((ext_vector_type(4))) float f32x4;    // MFMA C/D

__device__ __forceinline__ unsigned short f2bf(float f) {   // RNE f32->bf16
    union { float f; unsigned u; } v; v.f = f;
    unsigned r = v.u + 0x7FFFu + ((v.u >> 16) & 1u);
    return (unsigned short)(r >> 16);
}
__device__ __forceinline__ unsigned pk2(float a, float b) {
    return (unsigned)f2bf(a) | ((unsigned)f2bf(b) << 16);
}

// ---------------------------------------------------------------------------
// Precompute MFMA A-fragments (bf16) for all 4 networks into ws.
// mfma_f32_16x16x32_bf16 A-layout: lane l holds A[row=l&15][k=(l>>4)*8+j], j=0..7.
// Frag f element order in ws: f*512 + lane*8 + j   (so a wave loads 16B/lane).
// Frag table per net u (fb = u*14):
//   fb+c        (c=0..3)        : L1  A_c[row][k] = W1f[k][16c+row]
//   fb+4+2c+kc  (c=0..3,kc=0..1): L2  A[row][k]   = W2[kc*32+k][16c+row]
//   fb+12+kc    (kc=0..1)       : L3  A[row][k]   = W3[kc*32+k][row]
// W1f rows: k<16 -> WA[k]=W1[k]-W1[32+k]; k>=16 -> WB[k-16]=W1[k]+W1[k+16]
// ---------------------------------------------------------------------------
__global__ void prep_frags(const float* __restrict__ W1, const float* __restrict__ W2,
                           const float* __restrict__ W3, unsigned short* __restrict__ wsb) {
    int e = blockIdx.x * 256 + threadIdx.x;       // 0 .. 56*512-1
    if (e >= 56 * 512) return;
    int f = e >> 9, idx = e & 511;
    int lane = idx >> 3, j = idx & 7;
    int row = lane & 15, g = lane >> 4;
    int k = g * 8 + j;                            // 0..31
    int u = f / 14, t = f % 14;
    float val;
    if (t < 4) {
        int h = 16 * t + row;
        const float* w = W1 + u * 3072;           // (48,64) row-major
        val = (k < 16) ? (w[k * 64 + h] - w[(32 + k) * 64 + h])
                       : (w[k * 64 + h] + w[(k + 16) * 64 + h]);
    } else if (t < 12) {
        int c = (t - 4) >> 1, kc = (t - 4) & 1;
        val = W2[u * 4096 + (kc * 32 + k) * 64 + 16 * c + row];
    } else {
        int kc = t - 12;
        val = W3[u * 1024 + (kc * 32 + k) * 16 + row];
    }
    wsb[e] = f2bf(val);
}

// ---------------------------------------------------------------------------
// z[b,n,d] = x[b,n,31-d]*exp(logs[d]) + bias[d]; init log_det[b].
// ---------------------------------------------------------------------------
__global__ void affine_rev(const float* __restrict__ x, const float* __restrict__ logs,
                           const float* __restrict__ bias, float* __restrict__ out) {
    __shared__ float ssc[IDIM], sbi[IDIM];
    int tid = threadIdx.x;
    if (tid < IDIM) { ssc[tid] = expf(logs[tid]); sbi[tid] = bias[tid]; }
    __syncthreads();
    size_t p = (size_t)blockIdx.x * blockDim.x + tid;
    if (p < (size_t)NBATCH * NPTS) {
        const float4* xr = (const float4*)(x + p * IDIM);
        float xv[IDIM];
#pragma unroll
        for (int q = 0; q < 8; ++q) {
            float4 v = xr[q];
            xv[q * 4 + 0] = v.x; xv[q * 4 + 1] = v.y; xv[q * 4 + 2] = v.z; xv[q * 4 + 3] = v.w;
        }
        float4* zr = (float4*)(out + p * IDIM);
#pragma unroll
        for (int q = 0; q < 8; ++q) {
            float4 v;
            v.x = xv[31 - (q * 4 + 0)] * ssc[q * 4 + 0] + sbi[q * 4 + 0];
            v.y = xv[31 - (q * 4 + 1)] * ssc[q * 4 + 1] + sbi[q * 4 + 1];
            v.z = xv[31 - (q * 4 + 2)] * ssc[q * 4 + 2] + sbi[q * 4 + 2];
            v.w = xv[31 - (q * 4 + 3)] * ssc[q * 4 + 3] + sbi[q * 4 + 3];
            zr[q] = v;
        }
    }
    if (blockIdx.x == 0 && tid < NBATCH) {
        float sl = 0.f;
#pragma unroll
        for (int d = 0; d < IDIM; ++d) sl += logs[d];
        out[(size_t)NBATCH * NPTS * IDIM + tid] = sl * (float)NPTS;
    }
}

// ---------------------------------------------------------------------------
// MFMA conv kernel. Block = 256 thr = 4 waves; wave u owns network u and its
// 14 weight fragments in registers; processes PPB points sequentially.
// Inter-layer transpose via per-wave LDS [col=16][k], stride 136 B, XOR-swizzled.
// Epilogue (after one barrier): z2 update + log_det from LDS-staged s/t.
// ---------------------------------------------------------------------------
__global__ __launch_bounds__(256, 2)
void knn_mfma(const int* __restrict__ knn, const unsigned short* __restrict__ wsb,
              const float* __restrict__ B1, const float* __restrict__ B2,
              const float* __restrict__ B3, float* __restrict__ out) {
    __shared__ __align__(16) char hbuf[4][2][16 * 136];   // per-wave h1/h2 staging
    __shared__ float stg[PPB * 4 * 16];                   // [pt][net][dim]

    const int tid = threadIdx.x;
    const int u = tid >> 6, lane = tid & 63;
    const int g = lane >> 4, x = lane & 15;
    const int pbase = blockIdx.x * PPB;
    const int bb = pbase >> 13;                           // batch (PPB divides 8192)
    const float* z = out;

    // --- weight fragments (persist across the point loop) ---
    bf16x8 a1[4], a2k0[4], a2k1[4], a30, a31;
    const int fb = u * 14;
#pragma unroll
    for (int c = 0; c < 4; ++c)
        a1[c] = *(const bf16x8*)(wsb + (size_t)(fb + c) * 512 + lane * 8);
#pragma unroll
    for (int c = 0; c < 4; ++c) {
        a2k0[c] = *(const bf16x8*)(wsb + (size_t)(fb + 4 + 2 * c + 0) * 512 + lane * 8);
        a2k1[c] = *(const bf16x8*)(wsb + (size_t)(fb + 4 + 2 * c + 1) * 512 + lane * 8);
    }
    a30 = *(const bf16x8*)(wsb + (size_t)(fb + 12) * 512 + lane * 8);
    a31 = *(const bf16x8*)(wsb + (size_t)(fb + 13) * 512 + lane * 8);

    // --- biases: lane owns rows 16c+4g..+3 of h^T (or 4g..+3 of o^T) ---
    f32x4 b1v[4], b2v[4], b3v;
#pragma unroll
    for (int c = 0; c < 4; ++c) {
        b1v[c] = *(const f32x4*)(B1 + u * 64 + 16 * c + 4 * g);
        b2v[c] = *(const f32x4*)(B2 + u * 64 + 16 * c + 4 * g);
    }
    b3v = *(const f32x4*)(B3 + u * 16 + 4 * g);

    char* hbA = &hbuf[u][0][0];
    char* hbB = &hbuf[u][1][0];
    const int sw = (x & 7) << 4;                          // XOR swizzle (16B granularity)
    int wo[4];
#pragma unroll
    for (int c = 0; c < 4; ++c) wo[c] = x * 136 + ((32 * c + 8 * g) ^ sw);
    const int ro0 = x * 136 + ((g * 16) ^ sw);
    const int ro1 = x * 136 + ((64 + g * 16) ^ sw);

    const f32x4 zz = {0.f, 0.f, 0.f, 0.f};

#pragma unroll 1
    for (int pt = 0; pt < PPB; ++pt) {
        const int p = pbase + pt;
        const int nbr = knn[(size_t)p * KNN + x];
        const float* crow = z + (size_t)p * IDIM;
        const float* nrow = z + ((size_t)bb * NPTS + nbr) * IDIM;
        const float* rp = (g < 2) ? crow : nrow;          // k<16: ctr, k>=16: nbr
        const int off = (g & 1) * 8;
        float4 fa = *(const float4*)(rp + off);
        float4 fbv = *(const float4*)(rp + off + 4);
        union { bf16x8 v; unsigned w[4]; } ef;
        ef.w[0] = pk2(fa.x, fa.y);   ef.w[1] = pk2(fa.z, fa.w);
        ef.w[2] = pk2(fbv.x, fbv.y); ef.w[3] = pk2(fbv.z, fbv.w);

        // L1: h1^T chunks
        f32x4 acc[4] = {zz, zz, zz, zz};
#pragma unroll
        for (int c = 0; c < 4; ++c)
            acc[c] = __builtin_amdgcn_mfma_f32_16x16x32_bf16(a1[c], ef.v, acc[c], 0, 0, 0);
#pragma unroll
        for (int c = 0; c < 4; ++c) {
            float v0 = fmaxf(acc[c][0] + b1v[c][0], 0.f);
            float v1 = fmaxf(acc[c][1] + b1v[c][1], 0.f);
            float v2 = fmaxf(acc[c][2] + b1v[c][2], 0.f);
            float v3 = fmaxf(acc[c][3] + b1v[c][3], 0.f);
            unsigned long long q = ((unsigned long long)pk2(v2, v3) << 32) | pk2(v0, v1);
            *(unsigned long long*)(hbA + wo[c]) = q;
        }

        // L2: read h1 B-frags, 8 MFMAs
        union { bf16x8 v; unsigned long long q[2]; } h0, h1;
        h0.q[0] = *(const unsigned long long*)(hbA + ro0);
        h0.q[1] = *(const unsigned long long*)(hbA + ro0 + 8);
        h1.q[0] = *(const unsigned long long*)(hbA + ro1);
        h1.q[1] = *(const unsigned long long*)(hbA + ro1 + 8);
        f32x4 acc2[4] = {zz, zz, zz, zz};
#pragma unroll
        for (int c = 0; c < 4; ++c)
            acc2[c] = __builtin_amdgcn_mfma_f32_16x16x32_bf16(a2k0[c], h0.v, acc2[c], 0, 0, 0);
#pragma unroll
        for (int c = 0; c < 4; ++c)
            acc2[c] = __builtin_amdgcn_mfma_f32_16x16x32_bf16(a2k1[c], h1.v, acc2[c], 0, 0, 0);
#pragma unroll
        for (int c = 0; c < 4; ++c) {
            float v0 = fmaxf(acc2[c][0] + b2v[c][0], 0.f);
            float v1 = fmaxf(acc2[c][1] + b2v[c][1], 0.f);
            float v2 = fmaxf(acc2[c][2] + b2v[c][2], 0.f);
            float v3 = fmaxf(acc2[c][3] + b2v[c][3], 0.f);
            unsigned long long q = ((unsigned long long)pk2(v2, v3) << 32) | pk2(v0, v1);
            *(unsigned long long*)(hbB + wo[c]) = q;
        }

        // L3: o^T (16 out dims x 16 neighbors)
        union { bf16x8 v; unsigned long long q[2]; } g0, g1;
        g0.q[0] = *(const unsigned long long*)(hbB + ro0);
        g0.q[1] = *(const unsigned long long*)(hbB + ro0 + 8);
        g1.q[0] = *(const unsigned long long*)(hbB + ro1);
        g1.q[1] = *(const unsigned long long*)(hbB + ro1 + 8);
        f32x4 ao = zz;
        ao = __builtin_amdgcn_mfma_f32_16x16x32_bf16(a30, g0.v, ao, 0, 0, 0);
        ao = __builtin_amdgcn_mfma_f32_16x16x32_bf16(a31, g1.v, ao, 0, 0, 0);
        float o0 = ao[0] + b3v[0], o1 = ao[1] + b3v[1];
        float o2 = ao[2] + b3v[2], o3 = ao[3] + b3v[3];

        // max over neighbors (cols = 16-lane group)
#pragma unroll
        for (int m = 1; m <= 8; m <<= 1) {
            o0 = fmaxf(o0, __shfl_xor(o0, m, 16));
            o1 = fmaxf(o1, __shfl_xor(o1, m, 16));
            o2 = fmaxf(o2, __shfl_xor(o2, m, 16));
            o3 = fmaxf(o3, __shfl_xor(o3, m, 16));
        }
        if (x == 0) {
            float4* sp = (float4*)&stg[(pt * 4 + u) * 16 + 4 * g];
            *sp = make_float4(o0, o1, o2, o3);
        }
    }
    __syncthreads();

    // --- epilogue: z2 update + log_det. 16 groups of 16 lanes = 16 points. ---
    {
        const int pu = u * 4 + g;                  // 0..15
        const int prow = pbase + pu;
        const size_t zoff = (size_t)prow * IDIM + 16 + x;
        float z2v = out[zoff];
        float s1 = stg[(pu * 4 + 0) * 16 + x];
        float t1 = stg[(pu * 4 + 1) * 16 + x];
        float s2 = stg[(pu * 4 + 2) * 16 + x];
        float t2 = stg[(pu * 4 + 3) * 16 + x];
        float sc1 = CLAMPV * TWO_OVER_PI * atanf(s1 * (1.0f / CLAMPV));
        float sc2 = CLAMPV * TWO_OVER_PI * atanf(s2 * (1.0f / CLAMPV));
        z2v = z2v * expf(sc1) + t1;
        z2v = z2v * expf(sc2) + t2;
        out[zoff] = z2v;
        float ss = sc1 + sc2;
        ss += __shfl_xor(ss, 1, 16);
        ss += __shfl_xor(ss, 2, 16);
        ss += __shfl_xor(ss, 4, 16);
        ss += __shfl_xor(ss, 8, 16);
        if (x == 0) atomicAdd(out + (size_t)NBATCH * NPTS * IDIM + bb, ss);
    }
}

extern "C" void kernel_launch(void* const* d_in, const int* in_sizes, int n_in,
                              void* d_out, int out_size, void* d_ws, size_t ws_size,
                              hipStream_t stream) {
    const float* x    = (const float*)d_in[0];
    const int*   knn  = (const int*)d_in[1];
    const float* logs = (const float*)d_in[2];
    const float* bias = (const float*)d_in[3];
    const float* W1   = (const float*)d_in[4];
    const float* b1   = (const float*)d_in[5];
    const float* W2   = (const float*)d_in[6];
    const float* b2   = (const float*)d_in[7];
    const float* W3   = (const float*)d_in[8];
    const float* b3   = (const float*)d_in[9];
    float* out = (float*)d_out;
    unsigned short* wsb = (unsigned short*)d_ws;   // 56 frags * 1024 B = 57344 B

    hipLaunchKernelGGL(prep_frags, dim3(112), dim3(256), 0, stream, W1, W2, W3, wsb);
    hipLaunchKernelGGL(affine_rev, dim3(512), dim3(256), 0, stream, x, logs, bias, out);
    hipLaunchKernelGGL(knn_mfma, dim3((NBATCH * NPTS) / PPB), dim3(256), 0, stream,
                       knn, wsb, b1, b2, b3, out);
}

// Round 4
// 354.581 us; speedup vs baseline: 22.9527x; 1.3875x over previous
//
#include <hip/hip_runtime.h>
#include <math.h>

#define IDIM 32
#define KNN 16
#define NPTS 8192
#define NBATCH 16
#define PPB 16                      // points per block
#define CLAMPV 1.9f
#define TWO_OVER_PI 0.63661977236758134f

typedef __attribute__((ext_vector_type(8))) short bf16x8;   // 8 bf16 = 4 VGPR (MFMA A/B)
typedef __attribute__((ext_vector_type(4))) float f32x4;    // MFMA C/D

__device__ __forceinline__ unsigned short f2bf(float f) {   // RNE f32->bf16
    union { float f; unsigned u; } v; v.f = f;
    unsigned r = v.u + 0x7FFFu + ((v.u >> 16) & 1u);
    return (unsigned short)(r >> 16);
}
__device__ __forceinline__ unsigned pk2(float a, float b) {
    return (unsigned)f2bf(a) | ((unsigned)f2bf(b) << 16);
}

// ---------------------------------------------------------------------------
// Precompute MFMA A-fragments (bf16) for all 4 networks into ws.
// mfma_f32_16x16x32_bf16 A-layout: lane l holds A[row=l&15][k=(l>>4)*8+j], j=0..7.
// Frag f element order in ws: f*512 + lane*8 + j.
// Frag table per net u (fb = u*14):
//   fb+c        (c=0..3)        : L1  A_c[row][k] = W1f[k][16c+row]
//   fb+4+2c+kc  (c=0..3,kc=0..1): L2  A[row][k]   = W2[kc*32+k][16c+row]
//   fb+12+kc    (kc=0..1)       : L3  A[row][k]   = W3[kc*32+k][row]
// W1f rows: k<16 -> WA[k]=W1[k]-W1[32+k]; k>=16 -> WB[k-16]=W1[k]+W1[k+16]
// ---------------------------------------------------------------------------
__global__ void prep_frags(const float* __restrict__ W1, const float* __restrict__ W2,
                           const float* __restrict__ W3, unsigned short* __restrict__ wsb) {
    int e = blockIdx.x * 256 + threadIdx.x;       // 0 .. 56*512-1
    if (e >= 56 * 512) return;
    int f = e >> 9, idx = e & 511;
    int lane = idx >> 3, j = idx & 7;
    int row = lane & 15, g = lane >> 4;
    int k = g * 8 + j;                            // 0..31
    int u = f / 14, t = f % 14;
    float val;
    if (t < 4) {
        int h = 16 * t + row;
        const float* w = W1 + u * 3072;           // (48,64) row-major
        val = (k < 16) ? (w[k * 64 + h] - w[(32 + k) * 64 + h])
                       : (w[k * 64 + h] + w[(k + 16) * 64 + h]);
    } else if (t < 12) {
        int c = (t - 4) >> 1, kc = (t - 4) & 1;
        val = W2[u * 4096 + (kc * 32 + k) * 64 + 16 * c + row];
    } else {
        int kc = t - 12;
        val = W3[u * 1024 + (kc * 32 + k) * 16 + row];
    }
    wsb[e] = f2bf(val);
}

// ---------------------------------------------------------------------------
// z[b,n,d] = x[b,n,31-d]*exp(logs[d]) + bias[d]; init log_det[b].
// ---------------------------------------------------------------------------
__global__ void affine_rev(const float* __restrict__ x, const float* __restrict__ logs,
                           const float* __restrict__ bias, float* __restrict__ out) {
    __shared__ float ssc[IDIM], sbi[IDIM];
    int tid = threadIdx.x;
    if (tid < IDIM) { ssc[tid] = expf(logs[tid]); sbi[tid] = bias[tid]; }
    __syncthreads();
    size_t p = (size_t)blockIdx.x * blockDim.x + tid;
    if (p < (size_t)NBATCH * NPTS) {
        const float4* xr = (const float4*)(x + p * IDIM);
        float xv[IDIM];
#pragma unroll
        for (int q = 0; q < 8; ++q) {
            float4 v = xr[q];
            xv[q * 4 + 0] = v.x; xv[q * 4 + 1] = v.y; xv[q * 4 + 2] = v.z; xv[q * 4 + 3] = v.w;
        }
        float4* zr = (float4*)(out + p * IDIM);
#pragma unroll
        for (int q = 0; q < 8; ++q) {
            float4 v;
            v.x = xv[31 - (q * 4 + 0)] * ssc[q * 4 + 0] + sbi[q * 4 + 0];
            v.y = xv[31 - (q * 4 + 1)] * ssc[q * 4 + 1] + sbi[q * 4 + 1];
            v.z = xv[31 - (q * 4 + 2)] * ssc[q * 4 + 2] + sbi[q * 4 + 2];
            v.w = xv[31 - (q * 4 + 3)] * ssc[q * 4 + 3] + sbi[q * 4 + 3];
            zr[q] = v;
        }
    }
    if (blockIdx.x == 0 && tid < NBATCH) {
        float sl = 0.f;
#pragma unroll
        for (int d = 0; d < IDIM; ++d) sl += logs[d];
        out[(size_t)NBATCH * NPTS * IDIM + tid] = sl * (float)NPTS;
    }
}

// ---------------------------------------------------------------------------
// MFMA conv kernel, 2-point ILP + gather prefetch.
// Block = 4 waves; wave u owns network u (14 weight frags in registers).
// Each iteration: two independent point-chains (A/B) interleaved; neighbor
// indices fetched 2 pairs ahead, feature rows 1 pair ahead.
// Per-point LDS staging buffer shared between h1/h2 (per-wave DS ops are
// in-order -> read-then-overwrite is safe).
// ---------------------------------------------------------------------------
__global__ __launch_bounds__(256, 2)
void knn_mfma(const int* __restrict__ knn, const unsigned short* __restrict__ wsb,
              const float* __restrict__ B1, const float* __restrict__ B2,
              const float* __restrict__ B3, float* __restrict__ out) {
    __shared__ __align__(16) char hbuf[4][2][16 * 136];   // [wave][point A/B][staging]
    __shared__ float stg[PPB * 4 * 16];                   // [pt][net][dim]
    __shared__ float ldsum[16];

    const int tid = threadIdx.x;
    const int u = tid >> 6, lane = tid & 63;
    const int g = lane >> 4, x = lane & 15;
    const int pbase = blockIdx.x * PPB;
    const int bb = pbase >> 13;                           // batch (PPB divides 8192)

    // --- weight fragments (persist across the point loop) ---
    bf16x8 a1[4], a2k0[4], a2k1[4], a30, a31;
    const int fb = u * 14;
#pragma unroll
    for (int c = 0; c < 4; ++c)
        a1[c] = *(const bf16x8*)(wsb + (size_t)(fb + c) * 512 + lane * 8);
#pragma unroll
    for (int c = 0; c < 4; ++c) {
        a2k0[c] = *(const bf16x8*)(wsb + (size_t)(fb + 4 + 2 * c + 0) * 512 + lane * 8);
        a2k1[c] = *(const bf16x8*)(wsb + (size_t)(fb + 4 + 2 * c + 1) * 512 + lane * 8);
    }
    a30 = *(const bf16x8*)(wsb + (size_t)(fb + 12) * 512 + lane * 8);
    a31 = *(const bf16x8*)(wsb + (size_t)(fb + 13) * 512 + lane * 8);

    f32x4 b1v[4], b2v[4], b3v;
#pragma unroll
    for (int c = 0; c < 4; ++c) {
        b1v[c] = *(const f32x4*)(B1 + u * 64 + 16 * c + 4 * g);
        b2v[c] = *(const f32x4*)(B2 + u * 64 + 16 * c + 4 * g);
    }
    b3v = *(const f32x4*)(B3 + u * 16 + 4 * g);

    char* bufA = &hbuf[u][0][0];
    char* bufB = &hbuf[u][1][0];
    const int sw = (x & 7) << 4;                          // XOR swizzle (16B granularity)
    int wo[4];
#pragma unroll
    for (int c = 0; c < 4; ++c) wo[c] = x * 136 + ((32 * c + 8 * g) ^ sw);
    const int ro0 = x * 136 + ((g * 16) ^ sw);
    const int ro1 = x * 136 + ((64 + g * 16) ^ sw);

    const int off = (g & 1) * 8;
    const int* kcol = knn + (size_t)pbase * KNN + x;
    const float* zb = out + (size_t)bb * NPTS * IDIM;     // batch base
    const f32x4 zz = {0.f, 0.f, 0.f, 0.f};

    // --- prologue: indices for pairs 0,1; features for pair 0 ---
    int iA1 = kcol[2 * 16], iB1 = kcol[3 * 16];
    float4 pA0, pA1, pB0, pB1, nA0, nA1, nB0, nB1;
    {
        int iA0 = kcol[0], iB0 = kcol[1 * 16];
        const float* rpA = (g < 2) ? out + (size_t)(pbase + 0) * IDIM : zb + (size_t)iA0 * IDIM;
        pA0 = *(const float4*)(rpA + off); pA1 = *(const float4*)(rpA + off + 4);
        const float* rpB = (g < 2) ? out + (size_t)(pbase + 1) * IDIM : zb + (size_t)iB0 * IDIM;
        pB0 = *(const float4*)(rpB + off); pB1 = *(const float4*)(rpB + off + 4);
    }

#pragma unroll 1
    for (int pp = 0; pp < PPB / 2; ++pp) {
        // prefetch indices (2 pairs ahead) and features (1 pair ahead)
        int iA2 = 0, iB2 = 0;
        if (pp < PPB / 2 - 2) { iA2 = kcol[(2 * pp + 4) * 16]; iB2 = kcol[(2 * pp + 5) * 16]; }
        if (pp < PPB / 2 - 1) {
            const float* rpA = (g < 2) ? out + (size_t)(pbase + 2 * pp + 2) * IDIM
                                       : zb + (size_t)iA1 * IDIM;
            nA0 = *(const float4*)(rpA + off); nA1 = *(const float4*)(rpA + off + 4);
            const float* rpB = (g < 2) ? out + (size_t)(pbase + 2 * pp + 3) * IDIM
                                       : zb + (size_t)iB1 * IDIM;
            nB0 = *(const float4*)(rpB + off); nB1 = *(const float4*)(rpB + off + 4);
        }

        // pack features
        union { bf16x8 v; unsigned w[4]; } efA, efB;
        efA.w[0] = pk2(pA0.x, pA0.y); efA.w[1] = pk2(pA0.z, pA0.w);
        efA.w[2] = pk2(pA1.x, pA1.y); efA.w[3] = pk2(pA1.z, pA1.w);
        efB.w[0] = pk2(pB0.x, pB0.y); efB.w[1] = pk2(pB0.z, pB0.w);
        efB.w[2] = pk2(pB1.x, pB1.y); efB.w[3] = pk2(pB1.z, pB1.w);

        // ---- L1 ----
        f32x4 aA[4] = {zz, zz, zz, zz}, aB[4] = {zz, zz, zz, zz};
#pragma unroll
        for (int c = 0; c < 4; ++c)
            aA[c] = __builtin_amdgcn_mfma_f32_16x16x32_bf16(a1[c], efA.v, aA[c], 0, 0, 0);
#pragma unroll
        for (int c = 0; c < 4; ++c)
            aB[c] = __builtin_amdgcn_mfma_f32_16x16x32_bf16(a1[c], efB.v, aB[c], 0, 0, 0);
#pragma unroll
        for (int c = 0; c < 4; ++c) {
            float v0 = fmaxf(aA[c][0] + b1v[c][0], 0.f);
            float v1 = fmaxf(aA[c][1] + b1v[c][1], 0.f);
            float v2 = fmaxf(aA[c][2] + b1v[c][2], 0.f);
            float v3 = fmaxf(aA[c][3] + b1v[c][3], 0.f);
            *(unsigned long long*)(bufA + wo[c]) =
                ((unsigned long long)pk2(v2, v3) << 32) | pk2(v0, v1);
        }
#pragma unroll
        for (int c = 0; c < 4; ++c) {
            float v0 = fmaxf(aB[c][0] + b1v[c][0], 0.f);
            float v1 = fmaxf(aB[c][1] + b1v[c][1], 0.f);
            float v2 = fmaxf(aB[c][2] + b1v[c][2], 0.f);
            float v3 = fmaxf(aB[c][3] + b1v[c][3], 0.f);
            *(unsigned long long*)(bufB + wo[c]) =
                ((unsigned long long)pk2(v2, v3) << 32) | pk2(v0, v1);
        }

        // ---- read h1, L2 ----
        union { bf16x8 v; unsigned long long q[2]; } h0A, h1A, h0B, h1B;
        h0A.q[0] = *(const unsigned long long*)(bufA + ro0);
        h0A.q[1] = *(const unsigned long long*)(bufA + ro0 + 8);
        h1A.q[0] = *(const unsigned long long*)(bufA + ro1);
        h1A.q[1] = *(const unsigned long long*)(bufA + ro1 + 8);
        h0B.q[0] = *(const unsigned long long*)(bufB + ro0);
        h0B.q[1] = *(const unsigned long long*)(bufB + ro0 + 8);
        h1B.q[0] = *(const unsigned long long*)(bufB + ro1);
        h1B.q[1] = *(const unsigned long long*)(bufB + ro1 + 8);
        f32x4 cA[4] = {zz, zz, zz, zz}, cB[4] = {zz, zz, zz, zz};
#pragma unroll
        for (int c = 0; c < 4; ++c) {
            cA[c] = __builtin_amdgcn_mfma_f32_16x16x32_bf16(a2k0[c], h0A.v, cA[c], 0, 0, 0);
            cB[c] = __builtin_amdgcn_mfma_f32_16x16x32_bf16(a2k0[c], h0B.v, cB[c], 0, 0, 0);
        }
#pragma unroll
        for (int c = 0; c < 4; ++c) {
            cA[c] = __builtin_amdgcn_mfma_f32_16x16x32_bf16(a2k1[c], h1A.v, cA[c], 0, 0, 0);
            cB[c] = __builtin_amdgcn_mfma_f32_16x16x32_bf16(a2k1[c], h1B.v, cB[c], 0, 0, 0);
        }
#pragma unroll
        for (int c = 0; c < 4; ++c) {
            float v0 = fmaxf(cA[c][0] + b2v[c][0], 0.f);
            float v1 = fmaxf(cA[c][1] + b2v[c][1], 0.f);
            float v2 = fmaxf(cA[c][2] + b2v[c][2], 0.f);
            float v3 = fmaxf(cA[c][3] + b2v[c][3], 0.f);
            *(unsigned long long*)(bufA + wo[c]) =
                ((unsigned long long)pk2(v2, v3) << 32) | pk2(v0, v1);
        }
#pragma unroll
        for (int c = 0; c < 4; ++c) {
            float v0 = fmaxf(cB[c][0] + b2v[c][0], 0.f);
            float v1 = fmaxf(cB[c][1] + b2v[c][1], 0.f);
            float v2 = fmaxf(cB[c][2] + b2v[c][2], 0.f);
            float v3 = fmaxf(cB[c][3] + b2v[c][3], 0.f);
            *(unsigned long long*)(bufB + wo[c]) =
                ((unsigned long long)pk2(v2, v3) << 32) | pk2(v0, v1);
        }

        // ---- read h2, L3 ----
        union { bf16x8 v; unsigned long long q[2]; } g0A, g1A, g0B, g1B;
        g0A.q[0] = *(const unsigned long long*)(bufA + ro0);
        g0A.q[1] = *(const unsigned long long*)(bufA + ro0 + 8);
        g1A.q[0] = *(const unsigned long long*)(bufA + ro1);
        g1A.q[1] = *(const unsigned long long*)(bufA + ro1 + 8);
        g0B.q[0] = *(const unsigned long long*)(bufB + ro0);
        g0B.q[1] = *(const unsigned long long*)(bufB + ro0 + 8);
        g1B.q[0] = *(const unsigned long long*)(bufB + ro1);
        g1B.q[1] = *(const unsigned long long*)(bufB + ro1 + 8);
        f32x4 oA = zz, oB = zz;
        oA = __builtin_amdgcn_mfma_f32_16x16x32_bf16(a30, g0A.v, oA, 0, 0, 0);
        oB = __builtin_amdgcn_mfma_f32_16x16x32_bf16(a30, g0B.v, oB, 0, 0, 0);
        oA = __builtin_amdgcn_mfma_f32_16x16x32_bf16(a31, g1A.v, oA, 0, 0, 0);
        oB = __builtin_amdgcn_mfma_f32_16x16x32_bf16(a31, g1B.v, oB, 0, 0, 0);

        float oA0 = oA[0] + b3v[0], oA1 = oA[1] + b3v[1];
        float oA2 = oA[2] + b3v[2], oA3 = oA[3] + b3v[3];
        float oB0 = oB[0] + b3v[0], oB1 = oB[1] + b3v[1];
        float oB2 = oB[2] + b3v[2], oB3 = oB[3] + b3v[3];
#pragma unroll
        for (int m = 1; m <= 8; m <<= 1) {
            oA0 = fmaxf(oA0, __shfl_xor(oA0, m, 16));
            oA1 = fmaxf(oA1, __shfl_xor(oA1, m, 16));
            oA2 = fmaxf(oA2, __shfl_xor(oA2, m, 16));
            oA3 = fmaxf(oA3, __shfl_xor(oA3, m, 16));
            oB0 = fmaxf(oB0, __shfl_xor(oB0, m, 16));
            oB1 = fmaxf(oB1, __shfl_xor(oB1, m, 16));
            oB2 = fmaxf(oB2, __shfl_xor(oB2, m, 16));
            oB3 = fmaxf(oB3, __shfl_xor(oB3, m, 16));
        }
        if (x == 0) {
            *(float4*)&stg[((2 * pp + 0) * 4 + u) * 16 + 4 * g] = make_float4(oA0, oA1, oA2, oA3);
            *(float4*)&stg[((2 * pp + 1) * 4 + u) * 16 + 4 * g] = make_float4(oB0, oB1, oB2, oB3);
        }

        // rotate prefetched state
        pA0 = nA0; pA1 = nA1; pB0 = nB0; pB1 = nB1;
        iA1 = iA2; iB1 = iB2;
    }
    __syncthreads();

    // --- epilogue: z2 update + log_det (one atomic per block) ---
    {
        const int pu = u * 4 + g;                  // 0..15
        const int prow = pbase + pu;
        const size_t zoff = (size_t)prow * IDIM + 16 + x;
        float z2v = out[zoff];
        float s1 = stg[(pu * 4 + 0) * 16 + x];
        float t1 = stg[(pu * 4 + 1) * 16 + x];
        float s2 = stg[(pu * 4 + 2) * 16 + x];
        float t2 = stg[(pu * 4 + 3) * 16 + x];
        float sc1 = CLAMPV * TWO_OVER_PI * atanf(s1 * (1.0f / CLAMPV));
        float sc2 = CLAMPV * TWO_OVER_PI * atanf(s2 * (1.0f / CLAMPV));
        z2v = z2v * expf(sc1) + t1;
        z2v = z2v * expf(sc2) + t2;
        out[zoff] = z2v;
        float ss = sc1 + sc2;
        ss += __shfl_xor(ss, 1, 16);
        ss += __shfl_xor(ss, 2, 16);
        ss += __shfl_xor(ss, 4, 16);
        ss += __shfl_xor(ss, 8, 16);
        if (x == 0) ldsum[pu] = ss;
    }
    __syncthreads();
    if (tid == 0) {
        float tot = 0.f;
#pragma unroll
        for (int i = 0; i < 16; ++i) tot += ldsum[i];
        atomicAdd(out + (size_t)NBATCH * NPTS * IDIM + bb, tot);
    }
}

extern "C" void kernel_launch(void* const* d_in, const int* in_sizes, int n_in,
                              void* d_out, int out_size, void* d_ws, size_t ws_size,
                              hipStream_t stream) {
    const float* x    = (const float*)d_in[0];
    const int*   knn  = (const int*)d_in[1];
    const float* logs = (const float*)d_in[2];
    const float* bias = (const float*)d_in[3];
    const float* W1   = (const float*)d_in[4];
    const float* b1   = (const float*)d_in[5];
    const float* W2   = (const float*)d_in[6];
    const float* b2   = (const float*)d_in[7];
    const float* W3   = (const float*)d_in[8];
    const float* b3   = (const float*)d_in[9];
    float* out = (float*)d_out;
    unsigned short* wsb = (unsigned short*)d_ws;   // 56 frags * 1024 B = 57344 B

    hipLaunchKernelGGL(prep_frags, dim3(112), dim3(256), 0, stream, W1, W2, W3, wsb);
    hipLaunchKernelGGL(affine_rev, dim3(512), dim3(256), 0, stream, x, logs, bias, out);
    hipLaunchKernelGGL(knn_mfma, dim3((NBATCH * NPTS) / PPB), dim3(256), 0, stream,
                       knn, wsb, b1, b2, b3, out);
}